// Round 5
// baseline (680.902 us; speedup 1.0000x reference)
//
#include <hip/hip_runtime.h>
#include <hip/hip_bf16.h>

typedef __hip_bfloat16 bf16;
typedef __attribute__((ext_vector_type(8))) short short8;
typedef __attribute__((ext_vector_type(4))) short short4v;
typedef __attribute__((ext_vector_type(4))) float f32x4;

#define C_DIM 180
#define CPAD  192
#define NHEAD 6
#define HD    30
#define HID   720
#define HPAD  768
#define LN_EPS 1e-5f
#define IMG_TOK 16384   // 128*128 tokens per image
#define QSCALE 0.18257418583505536f

static __device__ __forceinline__ bf16 f2bf(float f) { return __float2bfloat16(f); }
static __device__ __forceinline__ float bf2f(bf16 v) { return __bfloat162float(v); }
static __device__ __forceinline__ short bfbits(float f) {
    bf16 b = __float2bfloat16(f); return *reinterpret_cast<short*>(&b);
}

// ---------------- weight prep: f32 [K][N] -> bf16 transposed padded [Npad][Kpad] ----------------
__global__ __launch_bounds__(256) void prep_w(const float* __restrict__ w, bf16* __restrict__ bt,
                                              int K, int N, int Kpad, int Npad) {
    int idx = blockIdx.x * 256 + threadIdx.x;
    if (idx >= Kpad * Npad) return;
    int k = idx % Kpad, n = idx / Kpad;
    float v = (k < K && n < N) ? w[(long)k * N + n] : 0.f;
    bt[idx] = f2bf(v);
}

// ---------------- bias prep: tbl[225][6] -> bias_frag[h][fi][fj][lane] f32x4 ----------------
__global__ __launch_bounds__(256) void prep_bias(const float* __restrict__ tbl,
                                                 float* __restrict__ bias_frag) {
    int idx = blockIdx.x * 256 + threadIdx.x;   // 6*4*4*64 = 6144
    if (idx >= 6144) return;
    int lane = idx & 63;
    int fj = (idx >> 6) & 3;
    int fi = (idx >> 8) & 3;
    int h  = idx >> 10;
    int g = lane >> 4, l15 = lane & 15;
    int kk = fj * 16 + l15;
    int rk = kk >> 3, ck = kk & 7;
    #pragma unroll
    for (int r = 0; r < 4; ++r) {
        int q = fi * 16 + g * 4 + r;
        int rq = q >> 3, cq = q & 7;
        int bidx = (rq - rk + 7) * 15 + (cq - ck + 7);
        bias_frag[idx * 4 + r] = tbl[bidx * NHEAD + h];
    }
}

// ---------------- LayerNorm: one wave per row of 180; writes stride-192, zero-padded ----------------
__global__ __launch_bounds__(256) void ln_kernel(const float* __restrict__ x,
                                                 const float* __restrict__ w,
                                                 const float* __restrict__ b,
                                                 bf16* __restrict__ out, int M) {
    int wave = threadIdx.x >> 6;
    int lane = threadIdx.x & 63;
    long row = (long)blockIdx.x * 4 + wave;
    if (row >= M) return;
    const float* xr = x + row * C_DIM;
    float e0 = xr[lane];
    float e1 = xr[lane + 64];
    float e2 = (lane < C_DIM - 128) ? xr[lane + 128] : 0.f;
    float s  = e0 + e1 + e2;
    float ss = e0*e0 + e1*e1 + e2*e2;
    #pragma unroll
    for (int off = 32; off > 0; off >>= 1) {
        s  += __shfl_xor(s,  off);
        ss += __shfl_xor(ss, off);
    }
    float mean = s * (1.f / C_DIM);
    float var  = ss * (1.f / C_DIM) - mean * mean;
    float rs   = rsqrtf(var + LN_EPS);
    bf16* orow = out + row * CPAD;
    orow[lane]      = f2bf((e0 - mean) * rs * w[lane]      + b[lane]);
    orow[lane + 64] = f2bf((e1 - mean) * rs * w[lane + 64] + b[lane + 64]);
    if (lane < C_DIM - 128)
        orow[lane + 128] = f2bf((e2 - mean) * rs * w[lane + 128] + b[lane + 128]);
    if (lane < CPAD - C_DIM)
        orow[C_DIM + lane] = f2bf(0.f);
}

// ---------------- MFMA GEMM ----------------
// OUT_MODE: 0 = bf16 linear, 1 = f32 linear (+resid), 2 = QKV split [Mc][6][32]x3
#define GLL16(gp, lp) \
    __builtin_amdgcn_global_load_lds((const __attribute__((address_space(1))) unsigned int*)(gp), \
                                     (__attribute__((address_space(3))) unsigned int*)(lp), 16, 0, 0)

template<int DO_GELU, int OUT_MODE>
__global__ __launch_bounds__(256) void mfma_gemm(
    const bf16* __restrict__ A, int lda,
    const bf16* __restrict__ Bt,            // [Npad][Kpad]
    const float* __restrict__ bias, int N,
    const float* __restrict__ resid, int nres,
    void* __restrict__ out, int ldo, int nstore,
    int Kpad, long matStride)
{
    __shared__ short As[128 * 64];
    __shared__ short Bs[64 * 64];
    int tid  = threadIdx.x;
    int lane = tid & 63;
    int wave = tid >> 6;
    int wm = wave >> 1, wn = wave & 1;
    long m0 = (long)blockIdx.y * 128;
    int  n0 = blockIdx.x * 64;

    f32x4 acc[4][2] = {};

    int nkt = Kpad >> 6;
    for (int kt = 0; kt < nkt; ++kt) {
        int k0 = kt << 6;
        #pragma unroll
        for (int i = 0; i < 4; ++i) {      // A tile: 128 rows x 8 chunks
            int f = i * 256 + tid;
            int r = f >> 3, c = f & 7;
            const bf16* gp = A + (m0 + r) * (long)lda + k0 + ((c ^ (r & 7)) << 3);
            GLL16(gp, &As[(i * 256 + (wave << 6)) * 8]);
        }
        #pragma unroll
        for (int i = 0; i < 2; ++i) {      // B tile: 64 rows x 8 chunks
            int f = i * 256 + tid;
            int r = f >> 3, c = f & 7;
            const bf16* gp = Bt + (n0 + r) * (long)Kpad + k0 + ((c ^ (r & 7)) << 3);
            GLL16(gp, &Bs[(i * 256 + (wave << 6)) * 8]);
        }
        __syncthreads();
        #pragma unroll
        for (int ks = 0; ks < 2; ++ks) {
            short8 af[4], bfr[2];
            #pragma unroll
            for (int fi = 0; fi < 4; ++fi) {
                int r  = wm * 64 + fi * 16 + (lane & 15);
                int ch = ks * 4 + (lane >> 4);
                af[fi] = *(const short8*)&As[r * 64 + ((ch ^ (r & 7)) << 3)];
            }
            #pragma unroll
            for (int fj = 0; fj < 2; ++fj) {
                int r  = wn * 32 + fj * 16 + (lane & 15);
                int ch = ks * 4 + (lane >> 4);
                bfr[fj] = *(const short8*)&Bs[r * 64 + ((ch ^ (r & 7)) << 3)];
            }
            #pragma unroll
            for (int fi = 0; fi < 4; ++fi)
                #pragma unroll
                for (int fj = 0; fj < 2; ++fj)
                    acc[fi][fj] = __builtin_amdgcn_mfma_f32_16x16x32_bf16(af[fi], bfr[fj], acc[fi][fj], 0, 0, 0);
        }
        __syncthreads();
    }

    #pragma unroll
    for (int fi = 0; fi < 4; ++fi) {
        #pragma unroll
        for (int fj = 0; fj < 2; ++fj) {
            int col = n0 + wn * 32 + fj * 16 + (lane & 15);
            if (col >= nstore) continue;
            float bv = bias[col];
            #pragma unroll
            for (int rg = 0; rg < 4; ++rg) {
                long row = m0 + wm * 64 + fi * 16 + (lane >> 4) * 4 + rg;
                float v = acc[fi][fj][rg] + bv;
                if (DO_GELU) v = 0.5f * v * (1.f + erff(v * 0.70710678118f));
                if (OUT_MODE == 1) {
                    if (resid) v += resid[row * (long)nres + col];
                    ((float*)out)[row * (long)ldo + col] = v;
                } else if (OUT_MODE == 0) {
                    ((bf16*)out)[row * (long)ldo + col] = f2bf(v);
                } else {
                    int mat = (col >= 360) ? 2 : (col >= 180 ? 1 : 0);
                    int rem = col - mat * 180;
                    int hh = rem / 30;
                    int dd = rem - hh * 30;
                    if (mat == 0) v *= QSCALE;
                    ((bf16*)out)[mat * matStride + row * 192 + hh * 32 + dd] = f2bf(v);
                }
            }
        }
    }
}

// ---------------- Fused MLP: out = GELU(x2n @ W1 + b1) @ W2 + b2 + x1 ----------------
// Block = 128 rows, 4 waves (2x2). h computed in 12 chunks of 64, staged via LDS.
__global__ __launch_bounds__(256) void mlp_fused(
    const bf16* __restrict__ x2n,       // [M][CPAD]
    const bf16* __restrict__ wf1t,      // [HPAD][CPAD]
    const float* __restrict__ f1b,      // [HID]
    const bf16* __restrict__ wf2t,      // [CPAD][HPAD]
    const float* __restrict__ f2b,      // [C_DIM]
    const float* __restrict__ x1,       // [M][C_DIM]
    float* __restrict__ out)            // [M][C_DIM]
{
    __shared__ __align__(16) short As[128 * 25 * 8];  // 128 rows x 24 chunks (+1 pad) = 50KB
    __shared__ __align__(16) short Hs[128 * 9 * 8];   // 128 rows x 8 chunks (+1 pad) = 18KB
    int tid = threadIdx.x;
    int lane = tid & 63;
    int wave = tid >> 6;
    int wm = wave >> 1, wn = wave & 1;
    int g = lane >> 4, l15 = lane & 15;
    long m0 = (long)blockIdx.x * 128;

    // ---- stage A = x2n[128][192] into LDS (24 chunks/row, stride 25) ----
    #pragma unroll
    for (int i = 0; i < 12; ++i) {
        int ch = i * 256 + tid;        // 0..3071
        int r = ch / 24, c = ch % 24;
        short8 v = *(const short8*)(x2n + (m0 + r) * CPAD + c * 8);
        *(short8*)&As[(r * 25 + c) * 8] = v;
    }
    __syncthreads();

    f32x4 acc2[4][6] = {};

    for (int hc = 0; hc < 12; ++hc) {
        // ---- stage 1: htile[128][64] = GELU(A @ wf1t[hc*64+..][:]^T + b1) ----
        f32x4 acc1[4][2] = {};
        #pragma unroll
        for (int ks = 0; ks < 6; ++ks) {
            short8 bfrg[2];
            #pragma unroll
            for (int fj = 0; fj < 2; ++fj)
                bfrg[fj] = *(const short8*)(wf1t + (long)(hc * 64 + wn * 32 + fj * 16 + l15) * CPAD + ks * 32 + g * 8);
            short8 af[4];
            #pragma unroll
            for (int fi = 0; fi < 4; ++fi)
                af[fi] = *(const short8*)&As[((wm * 64 + fi * 16 + l15) * 25 + ks * 4 + g) * 8];
            #pragma unroll
            for (int fi = 0; fi < 4; ++fi)
                #pragma unroll
                for (int fj = 0; fj < 2; ++fj)
                    acc1[fi][fj] = __builtin_amdgcn_mfma_f32_16x16x32_bf16(af[fi], bfrg[fj], acc1[fi][fj], 0, 0, 0);
        }
        __syncthreads();   // all waves done reading Hs of previous chunk
        // GELU + bf16 -> Hs
        #pragma unroll
        for (int fi = 0; fi < 4; ++fi)
            #pragma unroll
            for (int fj = 0; fj < 2; ++fj) {
                int col = wn * 32 + fj * 16 + l15;
                int hcol = hc * 64 + col;
                float bv = (hcol < HID) ? f1b[hcol] : 0.f;
                #pragma unroll
                for (int rg = 0; rg < 4; ++rg) {
                    int row = wm * 64 + fi * 16 + g * 4 + rg;
                    float v = acc1[fi][fj][rg] + bv;
                    v = 0.5f * v * (1.f + erff(v * 0.70710678118f));
                    Hs[row * 72 + col] = bfbits(v);
                }
            }
        __syncthreads();
        // ---- stage 2: acc2 += htile @ wf2t[:, hc*64..]^T ----
        #pragma unroll
        for (int ks = 0; ks < 2; ++ks) {
            short8 hf[4];
            #pragma unroll
            for (int fi = 0; fi < 4; ++fi)
                hf[fi] = *(const short8*)&Hs[((wm * 64 + fi * 16 + l15) * 9 + ks * 4 + g) * 8];
            short8 wf[6];
            #pragma unroll
            for (int fj = 0; fj < 6; ++fj)
                wf[fj] = *(const short8*)(wf2t + (long)(wn * 96 + fj * 16 + l15) * HPAD + hc * 64 + ks * 32 + g * 8);
            #pragma unroll
            for (int fi = 0; fi < 4; ++fi)
                #pragma unroll
                for (int fj = 0; fj < 6; ++fj)
                    acc2[fi][fj] = __builtin_amdgcn_mfma_f32_16x16x32_bf16(hf[fi], wf[fj], acc2[fi][fj], 0, 0, 0);
        }
    }

    // ---- epilogue: + f2b + x1 -> out (f32) ----
    #pragma unroll
    for (int fi = 0; fi < 4; ++fi)
        #pragma unroll
        for (int fj = 0; fj < 6; ++fj) {
            int col = wn * 96 + fj * 16 + l15;
            if (col >= C_DIM) continue;
            float bv = f2b[col];
            #pragma unroll
            for (int rg = 0; rg < 4; ++rg) {
                long row = m0 + wm * 64 + fi * 16 + g * 4 + rg;
                out[row * C_DIM + col] = acc2[fi][fj][rg] + bv + x1[row * C_DIM + col];
            }
        }
}

// ---------------- MFMA window attention: block = 1 window x 6 heads (384 thr) ----------------
__global__ __launch_bounds__(384, 3) void attn_mfma(
    const bf16* __restrict__ Qg, const bf16* __restrict__ Kg, const bf16* __restrict__ Vg,
    const float* __restrict__ bias_frag,    // [6][4][4][64] f32x4
    bf16* __restrict__ o)
{
    __shared__ __align__(16) short lds[6 * 4096];   // 8KB per wave
    int tid  = threadIdx.x;
    int wave = tid >> 6;            // = head
    int lane = tid & 63;
    int h = wave;
    int w = blockIdx.x;
    int b = w >> 8, rem = w & 255;
    int wi = rem >> 4, wj = rem & 15;
    long base = (long)b * IMG_TOK + wi * 8 * 128 + wj * 8;
    int g = lane >> 4, l15 = lane & 15;

    short* Vt = &lds[wave * 4096];          // [32][64] bf16, chunk-swizzled (c^=d&7)
    short* Ph = &lds[wave * 4096 + 2048];   // [64][32] bf16, chunk-swizzled

    short8 qf[4], kf[4];
    #pragma unroll
    for (int fi = 0; fi < 4; ++fi) {
        int q = fi * 16 + l15;
        long t = base + (q >> 3) * 128 + (q & 7);
        qf[fi] = *(const short8*)(Qg + (t * NHEAD + h) * 32 + g * 8);
        kf[fi] = *(const short8*)(Kg + (t * NHEAD + h) * 32 + g * 8);
    }
    if (g == 3) {
        #pragma unroll
        for (int fi = 0; fi < 4; ++fi) {
            qf[fi][6] = 0; qf[fi][7] = 0; kf[fi][6] = 0; kf[fi][7] = 0;
        }
    }

    {
        int t = lane;
        const bf16* vp = Vg + ((base + (t >> 3) * 128 + (t & 7)) * NHEAD + h) * 32;
        short8 v0 = *(const short8*)(vp);
        short8 v1 = *(const short8*)(vp + 8);
        short8 v2 = *(const short8*)(vp + 16);
        short8 v3 = *(const short8*)(vp + 24);
        v3[6] = 0; v3[7] = 0;
        int ct = t >> 3, t7 = t & 7;
        #pragma unroll
        for (int d = 0; d < 8; ++d)  Vt[d * 64 + ((ct ^ d) << 3) + t7] = v0[d];
        #pragma unroll
        for (int d = 8; d < 16; ++d) Vt[d * 64 + ((ct ^ (d & 7)) << 3) + t7] = v1[d - 8];
        #pragma unroll
        for (int d = 16; d < 24; ++d) Vt[d * 64 + ((ct ^ (d & 7)) << 3) + t7] = v2[d - 16];
        #pragma unroll
        for (int d = 24; d < 32; ++d) Vt[d * 64 + ((ct ^ (d & 7)) << 3) + t7] = v3[d - 24];
    }

    f32x4 S[4][4];
    #pragma unroll
    for (int fi = 0; fi < 4; ++fi)
        #pragma unroll
        for (int fj = 0; fj < 4; ++fj)
            S[fi][fj] = *(const f32x4*)(bias_frag + (((h * 4 + fi) * 4 + fj) * 64 + lane) * 4);
    #pragma unroll
    for (int fi = 0; fi < 4; ++fi)
        #pragma unroll
        for (int fj = 0; fj < 4; ++fj)
            S[fi][fj] = __builtin_amdgcn_mfma_f32_16x16x32_bf16(qf[fi], kf[fj], S[fi][fj], 0, 0, 0);

    f32x4 mrow[4], lsum[4];
    #pragma unroll
    for (int fi = 0; fi < 4; ++fi) {
        f32x4 a = S[fi][0], c = S[fi][2];
        #pragma unroll
        for (int cc = 0; cc < 4; ++cc) {
            a[cc] = fmaxf(a[cc], S[fi][1][cc]);
            c[cc] = fmaxf(c[cc], S[fi][3][cc]);
            a[cc] = fmaxf(a[cc], c[cc]);
        }
        mrow[fi] = a;
    }
    #pragma unroll
    for (int mask = 1; mask <= 8; mask <<= 1)
        #pragma unroll
        for (int fi = 0; fi < 4; ++fi)
            #pragma unroll
            for (int cc = 0; cc < 4; ++cc)
                mrow[fi][cc] = fmaxf(mrow[fi][cc], __shfl_xor(mrow[fi][cc], mask));
    #pragma unroll
    for (int fi = 0; fi < 4; ++fi)
        #pragma unroll
        for (int fj = 0; fj < 4; ++fj)
            #pragma unroll
            for (int cc = 0; cc < 4; ++cc)
                S[fi][fj][cc] = __expf(S[fi][fj][cc] - mrow[fi][cc]);
    #pragma unroll
    for (int fi = 0; fi < 4; ++fi) {
        f32x4 a = S[fi][0] + S[fi][1];
        f32x4 c = S[fi][2] + S[fi][3];
        lsum[fi] = a + c;
    }
    #pragma unroll
    for (int mask = 1; mask <= 8; mask <<= 1)
        #pragma unroll
        for (int fi = 0; fi < 4; ++fi)
            #pragma unroll
            for (int cc = 0; cc < 4; ++cc)
                lsum[fi][cc] += __shfl_xor(lsum[fi][cc], mask);

    f32x4 O[4][2] = {};
    #pragma unroll
    for (int ks = 0; ks < 2; ++ks) {
        #pragma unroll
        for (int fi = 0; fi < 4; ++fi)
            #pragma unroll
            for (int f2 = 0; f2 < 2; ++f2) {
                int fj = ks * 2 + f2;
                int kh = f2 * 16 + l15;
                #pragma unroll
                for (int r = 0; r < 4; ++r) {
                    int q = fi * 16 + g * 4 + r;
                    int c = (kh >> 3) ^ r ^ g;
                    Ph[q * 32 + (c << 3) + (kh & 7)] = bfbits(S[fi][fj][r]);
                }
            }
        short8 vf[2];
        #pragma unroll
        for (int f2 = 0; f2 < 2; ++f2) {
            int d = f2 * 16 + l15;
            int cv = (ks * 4 + g) ^ (d & 7);
            vf[f2] = *(const short8*)&Vt[d * 64 + (cv << 3)];
        }
        #pragma unroll
        for (int fi = 0; fi < 4; ++fi) {
            int q = fi * 16 + l15;
            int cr = g ^ (q & 3) ^ ((q >> 2) & 3);
            short8 pf = *(const short8*)&Ph[q * 32 + (cr << 3)];
            #pragma unroll
            for (int f2 = 0; f2 < 2; ++f2)
                O[fi][f2] = __builtin_amdgcn_mfma_f32_16x16x32_bf16(pf, vf[f2], O[fi][f2], 0, 0, 0);
        }
    }

    #pragma unroll
    for (int fi = 0; fi < 4; ++fi) {
        f32x4 inv;
        #pragma unroll
        for (int cc = 0; cc < 4; ++cc) inv[cc] = 1.f / lsum[fi][cc];
        #pragma unroll
        for (int r = 0; r < 4; ++r) {
            int q = fi * 16 + g * 4 + r;
            long t = base + (q >> 3) * 128 + (q & 7);
            bf16* op = o + t * CPAD + h * HD;
            op[l15] = f2bf(O[fi][0][r] * inv[r]);
            if (l15 < HD - 16)
                op[16 + l15] = f2bf(O[fi][1][r] * inv[r]);
        }
    }
    if (h == 0) {
        long t = base + (lane >> 3) * 128 + (lane & 7);
        bf16* op = o + t * CPAD + C_DIM;
        short4v z4 = {0, 0, 0, 0};
        short8  z8 = {0, 0, 0, 0, 0, 0, 0, 0};
        *(short4v*)(op) = z4;
        *(short8*)(op + 4) = z8;
    }
}

// ---------------- host launch ----------------
extern "C" void kernel_launch(void* const* d_in, const int* in_sizes, int n_in,
                              void* d_out, int out_size, void* d_ws, size_t ws_size,
                              hipStream_t stream) {
    const float* x    = (const float*)d_in[0];
    const float* n1w  = (const float*)d_in[1];
    const float* n1b  = (const float*)d_in[2];
    const float* qkvw = (const float*)d_in[3];
    const float* qkvb = (const float*)d_in[4];
    const float* tbl  = (const float*)d_in[5];
    const float* pw   = (const float*)d_in[6];
    const float* pb   = (const float*)d_in[7];
    const float* n2w  = (const float*)d_in[8];
    const float* n2b  = (const float*)d_in[9];
    const float* f1w  = (const float*)d_in[10];
    const float* f1b  = (const float*)d_in[11];
    const float* f2w  = (const float*)d_in[12];
    const float* f2b  = (const float*)d_in[13];

    auto al = [](size_t b) { return (b + 255) & ~(size_t)255; };
    char* base = (char*)d_ws;
    size_t off = 0;
    auto alloc = [&](size_t bytes) -> char* { char* p = base + off; off += al(bytes); return p; };

    bf16* wq  = (bf16*)alloc((size_t)576 * 192 * 2);
    bf16* wp  = (bf16*)alloc((size_t)192 * 192 * 2);
    bf16* wf1 = (bf16*)alloc((size_t)768 * 192 * 2);
    bf16* wf2 = (bf16*)alloc((size_t)192 * 768 * 2);
    float* bfr = (float*)alloc((size_t)6144 * 4 * 4);
    size_t woff = off;

    size_t r1_per = al((size_t)IMG_TOK * 576 * 2);    // Q/K/V [192]x3
    size_t r2_per = al((size_t)IMG_TOK * CPAD * 2);   // xn -> o -> x2n
    size_t r3_per = al((size_t)IMG_TOK * C_DIM * 4);  // x1 f32
    size_t per_img = r1_per + r2_per + r3_per;
    int g = 8;
    while (g > 1 && woff + per_img * (size_t)g > ws_size) g >>= 1;
    int nchunks = 8 / g;
    long Mc = (long)IMG_TOK * g;

    bf16*  R1 = (bf16*)(base + woff);
    bf16*  R2 = (bf16*)(base + woff + r1_per * g);
    float* R3 = (float*)(base + woff + (r1_per + r2_per) * g);
    long matStride = Mc * 192;
    bf16* Qg = R1;
    bf16* Kg = R1 + matStride;
    bf16* Vg = R1 + 2 * matStride;

    prep_w<<<(576 * 192 + 255) / 256, 256, 0, stream>>>(qkvw, wq, 180, 540, 192, 576);
    prep_w<<<(192 * 192 + 255) / 256, 256, 0, stream>>>(pw, wp, 180, 180, 192, 192);
    prep_w<<<(768 * 192 + 255) / 256, 256, 0, stream>>>(f1w, wf1, 180, 720, 192, 768);
    prep_w<<<(192 * 768 + 255) / 256, 256, 0, stream>>>(f2w, wf2, 720, 180, 768, 192);
    prep_bias<<<(6144 + 255) / 256, 256, 0, stream>>>(tbl, bfr);

    for (int ci = 0; ci < nchunks; ++ci) {
        const float* xc   = x + (size_t)ci * Mc * C_DIM;
        float*       outc = (float*)d_out + (size_t)ci * Mc * C_DIM;

        // 1. LN1 -> R2 (xn)
        ln_kernel<<<Mc / 4, 256, 0, stream>>>(xc, n1w, n1b, R2, (int)Mc);
        // 2. QKV -> Qg/Kg/Vg split, q pre-scaled
        mfma_gemm<0, 2><<<dim3(9, Mc / 128), 256, 0, stream>>>(
            R2, CPAD, wq, qkvb, 540, nullptr, 0, Qg, 0, 540, CPAD, matStride);
        // 3. MFMA window attention -> R2 (o)
        attn_mfma<<<dim3(256 * g), 384, 0, stream>>>(Qg, Kg, Vg, bfr, R2);
        // 4. proj + residual(x) -> R3 (x1, f32)
        mfma_gemm<0, 1><<<dim3(3, Mc / 128), 256, 0, stream>>>(
            R2, CPAD, wp, pb, 180, xc, 180, R3, 180, 180, CPAD, 0);
        // 5. LN2 -> R2 (x2n)
        ln_kernel<<<Mc / 4, 256, 0, stream>>>(R3, n2w, n2b, R2, (int)Mc);
        // 6+7. fused MLP -> out (f32)
        mlp_fused<<<dim3(Mc / 128), 256, 0, stream>>>(R2, wf1, f1b, wf2, f2b, R3, outc);
    }
}